// Round 7
// baseline (212.055 us; speedup 1.0000x reference)
//
#include <hip/hip_runtime.h>

// ============================================================================
// Algebraic collapse (layers 2..11 + head linear; A commutes with W):
//   out = A^10 x1 w~ + sum_l gamma_l A^(9-l) 1 + b_out
// Round-7: proven-correct protocol (sc1 everywhere cross-block), barrier
// re-engineered for latency:
//   * 256-thread blocks (4-wave __syncthreads, ~10x cheaper than 16-wave)
//   * graph group = 160 blocks (1000 gathers/CU/step, one latency window)
//   * densely-packed flags: 40 threads x 4 pipelined sc1 loads = 160 flags/RTT
//   * chain = 65 blocks, tagged dataflow (no barriers), exits early
//   * Horner gathers: sc1 loads (R4-proven correct; NO plain-cached gathers —
//     R6's stale-line race at slab boundaries is the documented failure)
// ============================================================================

#define N_NODES 10000
#define N_EDGES 160000
#define DEPTH   10

#define NB_G 160                 // graph blocks
#define NB_C 65                  // chain blocks (260 waves, 2 rows/wave)
#define NB   (NB_G + NB_C)       // 225 <= 256 CUs: all co-resident
#define BT   256
#define NTHG (NB_G * BT)         // 40960 graph threads
#define NPB  63                  // nodes per graph block (160*63 >= 10000)
#define ECAP 3072                // LDS edge-slice cap (expected ~1008)
#define RSTRIDE 10240            // floats per r-slab (line-clean)

typedef unsigned long long u64;

// ---- agent-scope (L3-coherent, L2-bypassing) accessors ---------------------
__device__ __forceinline__ int ldAi(const int* p) {
    return __hip_atomic_load(p, __ATOMIC_RELAXED, __HIP_MEMORY_SCOPE_AGENT);
}
__device__ __forceinline__ void stAi(int* p, int v) {
    __hip_atomic_store(p, v, __ATOMIC_RELAXED, __HIP_MEMORY_SCOPE_AGENT);
}
__device__ __forceinline__ float ldAf(const float* p) {
    return __hip_atomic_load(p, __ATOMIC_RELAXED, __HIP_MEMORY_SCOPE_AGENT);
}
__device__ __forceinline__ void stAf(float* p, float v) {
    __hip_atomic_store(p, v, __ATOMIC_RELAXED, __HIP_MEMORY_SCOPE_AGENT);
}
__device__ __forceinline__ u64 ld8(const u64* p) {
    return __hip_atomic_load(p, __ATOMIC_RELAXED, __HIP_MEMORY_SCOPE_AGENT);
}
__device__ __forceinline__ void st8(u64* p, u64 v) {
    __hip_atomic_store(p, v, __ATOMIC_RELAXED, __HIP_MEMORY_SCOPE_AGENT);
}
__device__ __forceinline__ u64 packf(float f) {
    union { float f; unsigned u; } c; c.f = f;
    return (1ull << 32) | (u64)c.u;
}
__device__ __forceinline__ float unpackf(u64 v) {
    union { unsigned u; float f; } c; c.u = (unsigned)v;
    return c.f;
}
#define READY(v) ((unsigned)((v) >> 32) != 0u)

__device__ __forceinline__ float pollf(const u64* p) {
    u64 v = ld8(p);
    while (!READY(v)) { __builtin_amdgcn_s_sleep(1); v = ld8(p); }
    return unpackf(v);
}

// ---- 160-block flag barrier, packed flags, 4-wave blocks -------------------
__device__ __forceinline__ void gbar(int* flags, int bx, int target) {
    asm volatile("s_waitcnt vmcnt(0)" ::: "memory");  // this wave's sc1 at L3
    __syncthreads();                                  // all 4 waves drained
    const int tx = threadIdx.x;
    if (tx == 0) stAi(&flags[bx], target);
    if (tx < 40) {                                    // 40 threads x 4 flags
        const int b0 = tx * 4;
        int f0 = ldAi(&flags[b0]),     f1 = ldAi(&flags[b0 + 1]);
        int f2 = ldAi(&flags[b0 + 2]), f3 = ldAi(&flags[b0 + 3]);
        while (f0 < target || f1 < target || f2 < target || f3 < target) {
            __builtin_amdgcn_s_sleep(1);
            if (f0 < target) f0 = ldAi(&flags[b0]);
            if (f1 < target) f1 = ldAi(&flags[b0 + 1]);
            if (f2 < target) f2 = ldAi(&flags[b0 + 2]);
            if (f3 < target) f3 = ldAi(&flags[b0 + 3]);
        }
    }
    __syncthreads();
}

extern "C" __global__ void __launch_bounds__(BT, 1) gcn_mega(
    const float* __restrict__ features, const float* __restrict__ W_in,
    const float* __restrict__ b_in, const float* __restrict__ Ws,
    const float* __restrict__ bs, const float* __restrict__ W_out,
    const float* __restrict__ b_out, const int* __restrict__ src,
    const int* __restrict__ dst, float* __restrict__ out,
    int* g_arrive, int* deg_done, int* scan_done, u64* gamma8, u64* vslab,
    int* deg, u64* esrc8, int* row_ptr, int* cursor, float* rslab)
{
    __shared__ int   lds_e[ECAP];     // 12 KB  edge slice (src ids)
    __shared__ float s_Wb[4096];      // 16 KB  [512][8]: {W_in col (6), b, pad}
    __shared__ float s_vt[512];       //  2 KB  vtilde
    __shared__ float s_gam[16];
    __shared__ int   s_info[2];
    __shared__ int   s_wsum[4];

    const int tx = threadIdx.x;
    const int bx = blockIdx.x;

    // ======================= CHAIN GROUP (blocks >= NB_G) ===================
    // Tagged dataflow, no barriers. Wave cw owns jobs {cw, cw+260} (<=512;
    // job 512 = gamma). 10 serial steps; stores tagged; exits.
    if (bx >= NB_G) {
        const int cw   = (bx - NB_G) * 4 + (tx >> 6);   // 0..259
        const int lane = tx & 63;
        const int j0 = cw, j1 = cw + 260;
        if (j0 > 512) return;
        const bool two = (j1 <= 512);
        for (int s = 0; s < DEPTH; s++) {
            const int l = 9 - s;
            const float* r0 = (j0 < 512)
                ? (Ws + (size_t)l * (512 * 512) + (size_t)j0 * 512)
                : (bs + (size_t)l * 512);
            float w0[8];
#pragma unroll
            for (int c = 0; c < 8; c++) w0[c] = r0[lane + 64 * c];
            float w1[8];
            if (two) {
                const float* r1 = (j1 < 512)
                    ? (Ws + (size_t)l * (512 * 512) + (size_t)j1 * 512)
                    : (bs + (size_t)l * 512);
#pragma unroll
                for (int c = 0; c < 8; c++) w1[c] = r1[lane + 64 * c];
            }
            float vin[8];
            if (s == 0) {
#pragma unroll
                for (int c = 0; c < 8; c++) vin[c] = W_out[lane + 64 * c];
            } else {
                const u64* vb = vslab + (size_t)s * 512;
                u64 raw[8];
#pragma unroll
                for (int c = 0; c < 8; c++) raw[c] = ld8(vb + lane + 64 * c);
                for (;;) {
                    bool ok = true;
#pragma unroll
                    for (int c = 0; c < 8; c++)
                        if (!READY(raw[c])) { ok = false; raw[c] = ld8(vb + lane + 64 * c); }
                    if (ok) break;
                    __builtin_amdgcn_s_sleep(1);
                }
#pragma unroll
                for (int c = 0; c < 8; c++) vin[c] = unpackf(raw[c]);
            }
            float a0 = 0.f, a1 = 0.f;
#pragma unroll
            for (int c = 0; c < 8; c++) {
                a0 += w0[c] * vin[c];
                if (two) a1 += w1[c] * vin[c];
            }
#pragma unroll
            for (int off = 32; off; off >>= 1) {
                a0 += __shfl_xor(a0, off, 64);
                if (two) a1 += __shfl_xor(a1, off, 64);
            }
            if (lane == 0) {
                if (j0 < 512) st8(vslab + (size_t)(s + 1) * 512 + j0, packf(a0));
                else          st8(gamma8 + l, packf(a0));
                if (two) {
                    if (j1 < 512) st8(vslab + (size_t)(s + 1) * 512 + j1, packf(a1));
                    else          st8(gamma8 + l, packf(a1));
                }
            }
        }
        return;   // w~ tags in vslab[10] ARE the rendezvous
    }

    // ======================= GRAPH GROUP (blocks < NB_G) ====================

    // -------- P0: degree count + per-block W_in pack ------------------------
    {
        const int t0 = bx * BT + tx;
        for (int e = t0; e < N_EDGES; e += NTHG) atomicAdd(&deg[dst[e]], 1);
    }
    for (int idx = tx; idx < 4096; idx += BT) {
        int j = idx >> 3, k = idx & 7;
        float v = 0.f;
        if (k < 6) v = W_in[k * 512 + j];          // read-only cached loads
        else if (k == 6) v = b_in[j];
        s_Wb[idx] = v;
    }
    asm volatile("s_waitcnt vmcnt(0)" ::: "memory");  // atomics at L3
    __syncthreads();
    if (tx == 0) stAi(&deg_done[bx], 1);

    // -------- P1: prefix scan (block 0, 40 values/thread in regs) -----------
    if (bx == 0) {
        if (tx < 40) {                              // gather 160 done-flags
            const int b0 = tx * 4;
            int f0 = ldAi(&deg_done[b0]),     f1 = ldAi(&deg_done[b0 + 1]);
            int f2 = ldAi(&deg_done[b0 + 2]), f3 = ldAi(&deg_done[b0 + 3]);
            while (!(f0 & f1 & f2 & f3)) {
                __builtin_amdgcn_s_sleep(1);
                if (!f0) f0 = ldAi(&deg_done[b0]);
                if (!f1) f1 = ldAi(&deg_done[b0 + 1]);
                if (!f2) f2 = ldAi(&deg_done[b0 + 2]);
                if (!f3) f3 = ldAi(&deg_done[b0 + 3]);
            }
        }
        __syncthreads();
        const int lane = tx & 63, wid = tx >> 6;    // 4 waves
        const int base = tx * 40;                   // 256*40 = 10240
        const bool sact = base < N_NODES;
        int lv[40];
        int ssum = 0;
        if (sact) {
#pragma unroll
            for (int i = 0; i < 40; i++) { lv[i] = ldAi(&deg[base + i]); ssum += lv[i]; }
        }
        int v = ssum;                               // wave inclusive scan
#pragma unroll
        for (int off = 1; off < 64; off <<= 1) {
            int u = __shfl_up(v, off, 64);
            if (lane >= off) v += u;
        }
        if (lane == 63) s_wsum[wid] = v;
        __syncthreads();
        if (wid == 0) {
            int w = (lane < 4) ? s_wsum[lane] : 0;
#pragma unroll
            for (int off = 1; off < 4; off <<= 1) {
                int u = __shfl_up(w, off, 64);
                if (lane >= off) w += u;
            }
            if (lane < 4) s_wsum[lane] = w;
        }
        __syncthreads();
        if (sact) {
            int run = (wid ? s_wsum[wid - 1] : 0) + (v - ssum);   // exclusive
#pragma unroll
            for (int i = 0; i < 40; i++) {
                stAi(&row_ptr[base + i], run);
                stAi(&cursor[base + i], run);
                run += lv[i];
            }
            if (tx == 249) stAi(&row_ptr[N_NODES], run);  // owns node 9999
        }
        asm volatile("s_waitcnt vmcnt(0)" ::: "memory");
        __syncthreads();
        if (tx == 0) stAi(scan_done, 1);
    } else {
        if (tx == 0) {
            while (ldAi(scan_done) < 1) __builtin_amdgcn_s_sleep(1);
        }
        __syncthreads();
    }

    // -------- P2: CSR fill (tagged entries; no completion barrier) ----------
    {
        const int t0 = bx * BT + tx;
        for (int e = t0; e < N_EDGES; e += NTHG) {
            int d = dst[e];
            unsigned sv = (unsigned)src[e];
            int pos = atomicAdd(&cursor[d], 1);
            st8(&esrc8[pos], (1ull << 32) | (u64)sv);
        }
    }

    // -------- P3: stage edge slice -> LDS (poll tags); feature agg ----------
    const int lo_node = (bx * NPB < N_NODES) ? bx * NPB : N_NODES;
    const int hi_node = (bx * NPB + NPB < N_NODES) ? bx * NPB + NPB : N_NODES;
    if (tx == 0) {
        s_info[0] = ldAi(&row_ptr[lo_node]);
        s_info[1] = ldAi(&row_ptr[hi_node]);
    }
    __syncthreads();
    const int e_lo = s_info[0];
    const int slen = s_info[1] - e_lo;
    const bool use_lds = (slen <= ECAP);
    if (use_lds) {
        for (int i = tx; i < slen; i += BT) {
            u64 v = ld8(&esrc8[e_lo + i]);
            while (!READY(v)) { __builtin_amdgcn_s_sleep(1); v = ld8(&esrc8[e_lo + i]); }
            lds_e[i] = (int)(unsigned)v;
        }
    }
    __syncthreads();

    const int node = bx * NPB + (tx >> 2);          // 4 threads/node
    const int sub  = tx & 3;
    const bool act = (tx < 4 * NPB) && (node < N_NODES);
    int ns = 0, ne = 0;
    float a0 = 0.f, a1 = 0.f, a2 = 0.f, a3 = 0.f, a4 = 0.f, a5 = 0.f;
    if (act) {
        ns = ldAi(&row_ptr[node]);
        ne = ldAi(&row_ptr[node + 1]);
        for (int pp = ns + sub; pp < ne; pp += 4) {
            int j;
            if (use_lds) j = lds_e[pp - e_lo];
            else {
                u64 v = ld8(&esrc8[pp]);
                while (!READY(v)) { __builtin_amdgcn_s_sleep(1); v = ld8(&esrc8[pp]); }
                j = (int)(unsigned)v;
            }
            const float2* f = (const float2*)(features + (size_t)j * 6);
            float2 f0 = f[0], f1 = f[1], f2 = f[2];
            a0 += f0.x; a1 += f0.y; a2 += f1.x;
            a3 += f1.y; a4 += f2.x; a5 += f2.y;
        }
        a0 += __shfl_xor(a0, 1, 64); a0 += __shfl_xor(a0, 2, 64);
        a1 += __shfl_xor(a1, 1, 64); a1 += __shfl_xor(a1, 2, 64);
        a2 += __shfl_xor(a2, 1, 64); a2 += __shfl_xor(a2, 2, 64);
        a3 += __shfl_xor(a3, 1, 64); a3 += __shfl_xor(a3, 2, 64);
        a4 += __shfl_xor(a4, 1, 64); a4 += __shfl_xor(a4, 2, 64);
        a5 += __shfl_xor(a5, 1, 64); a5 += __shfl_xor(a5, 2, 64);
    }

    // -------- stage vtilde + gamma (poll chain tags) ------------------------
    s_vt[tx]       = pollf(vslab + 10 * 512 + tx);
    s_vt[tx + 256] = pollf(vslab + 10 * 512 + tx + 256);
    if (tx < DEPTH) s_gam[tx] = pollf(gamma8 + tx);
    __syncthreads();

    // -------- proj: r0 = relu(a . W_in + b_in) . w~ -> rslab[0] -------------
    if (act) {
        const float4* Wb4 = (const float4*)s_Wb;
        float zacc = 0.f;
#pragma unroll 4
        for (int jj = 0; jj < 128; jj++) {
            int j = (jj << 2) | sub;                // 4-way split of j-range
            float4 wA = Wb4[2 * j];                 // w0..w3
            float4 wB = Wb4[2 * j + 1];             // w4, w5, b, pad
            float tv = wB.z + a0 * wA.x + a1 * wA.y + a2 * wA.z +
                       a3 * wA.w + a4 * wB.x + a5 * wB.y;
            zacc += fmaxf(tv, 0.f) * s_vt[j];
        }
        zacc += __shfl_xor(zacc, 1, 64);
        zacc += __shfl_xor(zacc, 2, 64);
        if (sub == 0) stAf(&rslab[node], zacc);
    }
    int gt = 1;
    gbar(g_arrive, bx, gt++);

    // -------- Horner: r_{l+1} = A r_l + gamma[l]; sc1 gathers (proven) ------
    for (int l = 0; l < DEPTH; l++) {
        if (act) {
            const float* rin = rslab + (size_t)l * RSTRIDE;
            float h0 = 0.f, h1 = 0.f, h2 = 0.f, h3 = 0.f;
            int pp = ns + sub;
            if (use_lds) {
                for (; pp + 12 < ne; pp += 16) {
                    h0 += ldAf(&rin[lds_e[pp - e_lo]]);
                    h1 += ldAf(&rin[lds_e[pp + 4 - e_lo]]);
                    h2 += ldAf(&rin[lds_e[pp + 8 - e_lo]]);
                    h3 += ldAf(&rin[lds_e[pp + 12 - e_lo]]);
                }
                for (; pp < ne; pp += 4) h0 += ldAf(&rin[lds_e[pp - e_lo]]);
            } else {
                for (; pp < ne; pp += 4) {
                    u64 ev = ld8(&esrc8[pp]);
                    while (!READY(ev)) { __builtin_amdgcn_s_sleep(1); ev = ld8(&esrc8[pp]); }
                    h0 += ldAf(&rin[(int)(unsigned)ev]);
                }
            }
            float hs = (h0 + h1) + (h2 + h3);
            hs += __shfl_xor(hs, 1, 64);
            hs += __shfl_xor(hs, 2, 64);
            if (sub == 0) {
                float res = hs + s_gam[l];
                if (l == DEPTH - 1) out[node] = res + b_out[0];
                else stAf(&rslab[(size_t)(l + 1) * RSTRIDE + node], res);
            }
        }
        if (l < DEPTH - 1) gbar(g_arrive, bx, gt++);
    }
}

// ---------------- launch ----------------

extern "C" void kernel_launch(void* const* d_in, const int* in_sizes, int n_in,
                              void* d_out, int out_size, void* d_ws, size_t ws_size,
                              hipStream_t stream) {
    const float* features = (const float*)d_in[0];  // [10000, 6]
    const float* W_in     = (const float*)d_in[1];  // [6, 512]
    const float* b_in     = (const float*)d_in[2];  // [512]
    const float* Ws       = (const float*)d_in[3];  // [10, 512, 512]
    const float* bs       = (const float*)d_in[4];  // [10, 512]
    const float* W_out    = (const float*)d_in[5];  // [512, 1]
    const float* b_out    = (const float*)d_in[6];  // [1]
    const int*   src      = (const int*)d_in[7];    // [160000]
    const int*   dst      = (const int*)d_in[8];    // [160000]
    float* out = (float*)d_out;                     // [10000]

    char* base = (char*)d_ws;
    // ---- zeroed region (flags/tags/deg cleared every replay) ----
    int* g_arrive  = (int*)(base + 0);          // 160*4 -> pad 1024
    int* deg_done  = (int*)(base + 1024);       // 160*4 -> pad 1024
    int* scan_done = (int*)(base + 2048);       // 128
    u64* gamma8    = (u64*)(base + 2176);       // 128
    u64* vslab     = (u64*)(base + 2304);       // 11*512*8 = 45056 -> 47360
    int* deg       = (int*)(base + 47360);      // 40000 -> 87360 (pad 87424)
    u64* esrc8     = (u64*)(base + 87424);      // 1280000 -> 1367424
    const size_t MEMSET_END = 1367424;
    // ---- non-zeroed (fully overwritten before any read, each launch) ----
    int*   row_ptr = (int*)(base + 1367424);    // 40004 -> pad 1407488
    int*   cursor  = (int*)(base + 1407488);    // 40000 -> 1447488 (pad 1447552)
    float* rslab   = (float*)(base + 1447552);  // 11*10240*4 = 450560 -> 1898112

    // clear tags/flags/deg each replay (captured in graph)
    hipMemsetAsync(base, 0, MEMSET_END, stream);

    gcn_mega<<<NB, BT, 0, stream>>>(features, W_in, b_in, Ws, bs, W_out, b_out,
                                    src, dst, out,
                                    g_arrive, deg_done, scan_done, gamma8,
                                    vslab, deg, esrc8, row_ptr, cursor, rslab);
}

// Round 8
// 206.002 us; speedup vs baseline: 1.0294x; 1.0294x over previous
//
#include <hip/hip_runtime.h>

// ============================================================================
// Algebraic collapse (layers 2..11 + head linear; A commutes with W):
//   out = A^10 x1 w~ + sum_l gamma_l A^(9-l) 1 + b_out
// Round-8: CONSOLIDATION. Exact composition of the two absmax==0-proven
// structures, nothing new:
//   * R4 back-end: 40 x 1024 graph blocks; group_bar (stride-32 flags, one
//     poll thread per flag); proj + 10 Horner steps on sc1 ping-pong rb0/rb1.
//   * R5 front-end: deg_done flags -> block-0 scan -> scan_done; tagged esrc8
//     CSR fill + tagged LDS staging; chain group = 33 x 1024 barrier-free
//     tagged dataflow (1 row/wave); graph blocks poll w~/gamma tags directly.
// rb0/rb1 are inside the memset region (race reads 0.0, not poison).
// NO plain loads/stores on any cross-block mutable data (R6 lesson).
// NO restructured barriers/geometry (R7 lesson - latent race, reverted).
// ============================================================================

#define N_NODES 10000
#define N_EDGES 160000
#define DEPTH   10

#define NB_G 40                  // graph blocks
#define NB_C 33                  // chain blocks (33*16 waves = 528 >= 513)
#define NB   (NB_G + NB_C)       // 73 blocks, 16 waves each: all co-resident
#define BT   1024
#define NTHG (NB_G * BT)         // 40960 graph threads
#define NPB  250                 // nodes per graph block (40*250 = 10000)
#define ECAP 8192                // LDS edge-slice cap (expected ~4000)

typedef unsigned long long u64;

// ---- agent-scope (L3-coherent) accessors -----------------------------------
__device__ __forceinline__ int ldAi(const int* p) {
    return __hip_atomic_load(p, __ATOMIC_RELAXED, __HIP_MEMORY_SCOPE_AGENT);
}
__device__ __forceinline__ void stAi(int* p, int v) {
    __hip_atomic_store(p, v, __ATOMIC_RELAXED, __HIP_MEMORY_SCOPE_AGENT);
}
__device__ __forceinline__ float ldAf(const float* p) {
    return __hip_atomic_load(p, __ATOMIC_RELAXED, __HIP_MEMORY_SCOPE_AGENT);
}
__device__ __forceinline__ void stAf(float* p, float v) {
    __hip_atomic_store(p, v, __ATOMIC_RELAXED, __HIP_MEMORY_SCOPE_AGENT);
}
__device__ __forceinline__ u64 ld8(const u64* p) {
    return __hip_atomic_load(p, __ATOMIC_RELAXED, __HIP_MEMORY_SCOPE_AGENT);
}
__device__ __forceinline__ void st8(u64* p, u64 v) {
    __hip_atomic_store(p, v, __ATOMIC_RELAXED, __HIP_MEMORY_SCOPE_AGENT);
}
__device__ __forceinline__ u64 packf(float f) {
    union { float f; unsigned u; } c; c.f = f;
    return (1ull << 32) | (u64)c.u;
}
__device__ __forceinline__ float unpackf(u64 v) {
    union { unsigned u; float f; } c; c.u = (unsigned)v;
    return c.f;
}
#define READY(v) ((unsigned)((v) >> 32) != 0u)

__device__ __forceinline__ float pollf(const u64* p) {
    u64 v = ld8(p);
    while (!READY(v)) { __builtin_amdgcn_s_sleep(1); v = ld8(p); }
    return unpackf(v);
}

// ---- R4-proven group barrier: stride-32 flags, one poll thread per flag ----
__device__ __forceinline__ void group_bar(int* flags, int gi, int n, int target) {
    const int tx = threadIdx.x;
    asm volatile("s_waitcnt vmcnt(0)" ::: "memory");  // this wave's sc1 at L3
    __syncthreads();                                  // all waves drained
    if (tx == 0) stAi(&flags[gi * 32], target);
    if (tx < n && tx != gi) {
        while (ldAi(&flags[tx * 32]) < target) __builtin_amdgcn_s_sleep(1);
    }
    __syncthreads();
}

extern "C" __global__ void __launch_bounds__(BT, 1) gcn_mega(
    const float* __restrict__ features, const float* __restrict__ W_in,
    const float* __restrict__ b_in, const float* __restrict__ Ws,
    const float* __restrict__ bs, const float* __restrict__ W_out,
    const float* __restrict__ b_out, const int* __restrict__ src,
    const int* __restrict__ dst, float* __restrict__ out,
    int* g_arrive, int* deg_done, int* scan_done, u64* gamma8, u64* vslab,
    int* deg, u64* esrc8, float* rb0, float* rb1, int* row_ptr, int* cursor)
{
    __shared__ int   lds_e[ECAP];     // 32 KB  edge slice (src ids)
    __shared__ float s_Wb[4096];      // 16 KB  [512][8]: {W_in col (6), b, pad}
    __shared__ float s_vt[512];       //  2 KB  vtilde
    __shared__ float s_gam[16];
    __shared__ int   s_info[2];
    __shared__ int   s_wsum[16];

    const int tx = threadIdx.x;
    const int bx = blockIdx.x;

    // ======================= CHAIN GROUP (blocks >= NB_G) ===================
    // R5-proven tagged dataflow, no barriers. Wave cw owns row cw (512=gamma).
    if (bx >= NB_G) {
        const int gi   = bx - NB_G;
        const int cw   = gi * 16 + (tx >> 6);         // 0..527
        const int lane = tx & 63;
        if (cw > 512) return;
        for (int s = 0; s < DEPTH; s++) {
            const int l = 9 - s;
            const float* rowp = (cw < 512)
                ? (Ws + (size_t)l * (512 * 512) + (size_t)cw * 512)
                : (bs + (size_t)l * 512);
            float wrow[8];
#pragma unroll
            for (int c = 0; c < 8; c++) wrow[c] = rowp[lane + 64 * c];
            float vin[8];
            if (s == 0) {
#pragma unroll
                for (int c = 0; c < 8; c++) vin[c] = W_out[lane + 64 * c];
            } else {
                const u64* vb = vslab + (size_t)s * 512;
                u64 raw[8];
#pragma unroll
                for (int c = 0; c < 8; c++) raw[c] = ld8(vb + lane + 64 * c);
                for (;;) {
                    bool ok = true;
#pragma unroll
                    for (int c = 0; c < 8; c++)
                        if (!READY(raw[c])) { ok = false; raw[c] = ld8(vb + lane + 64 * c); }
                    if (ok) break;
                    __builtin_amdgcn_s_sleep(1);
                }
#pragma unroll
                for (int c = 0; c < 8; c++) vin[c] = unpackf(raw[c]);
            }
            float acc = 0.f;
#pragma unroll
            for (int c = 0; c < 8; c++) acc += wrow[c] * vin[c];
#pragma unroll
            for (int off = 32; off; off >>= 1) acc += __shfl_xor(acc, off, 64);
            if (lane == 0) {
                if (cw < 512) st8(vslab + (size_t)(s + 1) * 512 + cw, packf(acc));
                else          st8(gamma8 + l, packf(acc));
            }
        }
        return;   // w~ tags in vslab[10] ARE the rendezvous
    }

    // ======================= GRAPH GROUP (blocks < NB_G) ====================

    // -------- P0: degree count + per-block W_in pack ------------------------
    {
        const int t0 = bx * BT + tx;
        for (int e = t0; e < N_EDGES; e += NTHG) atomicAdd(&deg[dst[e]], 1);
    }
    for (int idx = tx; idx < 4096; idx += BT) {
        int j = idx >> 3, k = idx & 7;
        float v = 0.f;
        if (k < 6) v = W_in[k * 512 + j];          // read-only cached loads
        else if (k == 6) v = b_in[j];
        s_Wb[idx] = v;
    }
    asm volatile("s_waitcnt vmcnt(0)" ::: "memory");  // atomics at L3
    __syncthreads();
    if (tx == 0) stAi(&deg_done[bx * 32], 1);

    // -------- P1: prefix scan (block 0) -> row_ptr, cursor, scan_done -------
    if (bx == 0) {
        if (tx < NB_G) {
            while (ldAi(&deg_done[tx * 32]) < 1) __builtin_amdgcn_s_sleep(1);
        }
        __syncthreads();
        const int lane = tx & 63, wid = tx >> 6;     // 16 waves
        const bool sact = tx < 1000;                 // 1000 x 10 = 10000
        int lv[10];
        int ssum = 0;
        if (sact) {
#pragma unroll
            for (int i = 0; i < 10; i++) { lv[i] = ldAi(&deg[tx * 10 + i]); ssum += lv[i]; }
        }
        int v = ssum;                                // wave inclusive scan
#pragma unroll
        for (int off = 1; off < 64; off <<= 1) {
            int u = __shfl_up(v, off, 64);
            if (lane >= off) v += u;
        }
        if (lane == 63) s_wsum[wid] = v;
        __syncthreads();
        if (wid == 0) {
            int w = (lane < 16) ? s_wsum[lane] : 0;
#pragma unroll
            for (int off = 1; off < 16; off <<= 1) {
                int u = __shfl_up(w, off, 64);
                if (lane >= off) w += u;
            }
            if (lane < 16) s_wsum[lane] = w;
        }
        __syncthreads();
        if (sact) {
            int run = (wid ? s_wsum[wid - 1] : 0) + (v - ssum);   // exclusive
#pragma unroll
            for (int i = 0; i < 10; i++) {
                stAi(&row_ptr[tx * 10 + i], run);
                stAi(&cursor[tx * 10 + i], run);
                run += lv[i];
            }
            if (tx == 999) stAi(&row_ptr[N_NODES], run);
        }
        asm volatile("s_waitcnt vmcnt(0)" ::: "memory");
        __syncthreads();
        if (tx == 0) stAi(scan_done, 1);
    } else {
        if (tx == 0) {
            while (ldAi(scan_done) < 1) __builtin_amdgcn_s_sleep(1);
        }
        __syncthreads();
    }

    // -------- P2: CSR fill (tagged entries; no completion barrier) ----------
    {
        const int t0 = bx * BT + tx;
        for (int e = t0; e < N_EDGES; e += NTHG) {
            int d = dst[e];
            unsigned sv = (unsigned)src[e];
            int pos = atomicAdd(&cursor[d], 1);
            st8(&esrc8[pos], (1ull << 32) | (u64)sv);
        }
    }

    // -------- P3: stage edge slice -> LDS (poll tags); feature agg ----------
    if (tx == 0) {
        s_info[0] = ldAi(&row_ptr[bx * NPB]);
        s_info[1] = ldAi(&row_ptr[bx * NPB + NPB]);
    }
    __syncthreads();
    const int e_lo = s_info[0];
    const int slen = s_info[1] - e_lo;
    const bool use_lds = (slen <= ECAP);
    if (use_lds) {
        for (int i = tx; i < slen; i += BT) {
            u64 v = ld8(&esrc8[e_lo + i]);
            while (!READY(v)) { __builtin_amdgcn_s_sleep(1); v = ld8(&esrc8[e_lo + i]); }
            lds_e[i] = (int)(unsigned)v;
        }
    }
    __syncthreads();

    const int node = bx * NPB + (tx >> 2);           // 4 threads/node
    const int sub  = tx & 3;
    const bool act = tx < 4 * NPB;                   // 1000 active threads
    int ns = 0, ne = 0;
    float a0 = 0.f, a1 = 0.f, a2 = 0.f, a3 = 0.f, a4 = 0.f, a5 = 0.f;
    if (act) {
        ns = ldAi(&row_ptr[node]);
        ne = ldAi(&row_ptr[node + 1]);
        for (int pp = ns + sub; pp < ne; pp += 4) {
            int j;
            if (use_lds) j = lds_e[pp - e_lo];
            else {
                u64 v = ld8(&esrc8[pp]);
                while (!READY(v)) { __builtin_amdgcn_s_sleep(1); v = ld8(&esrc8[pp]); }
                j = (int)(unsigned)v;
            }
            const float2* f = (const float2*)(features + (size_t)j * 6);
            float2 f0 = f[0], f1 = f[1], f2 = f[2];
            a0 += f0.x; a1 += f0.y; a2 += f1.x;
            a3 += f1.y; a4 += f2.x; a5 += f2.y;
        }
        a0 += __shfl_xor(a0, 1, 64); a0 += __shfl_xor(a0, 2, 64);
        a1 += __shfl_xor(a1, 1, 64); a1 += __shfl_xor(a1, 2, 64);
        a2 += __shfl_xor(a2, 1, 64); a2 += __shfl_xor(a2, 2, 64);
        a3 += __shfl_xor(a3, 1, 64); a3 += __shfl_xor(a3, 2, 64);
        a4 += __shfl_xor(a4, 1, 64); a4 += __shfl_xor(a4, 2, 64);
        a5 += __shfl_xor(a5, 1, 64); a5 += __shfl_xor(a5, 2, 64);
    }

    // -------- stage vtilde + gamma (poll chain tags; R5-proven) -------------
    if (tx < 512) s_vt[tx] = pollf(vslab + 10 * 512 + tx);
    else if (tx < 512 + DEPTH) s_gam[tx - 512] = pollf(gamma8 + (tx - 512));
    __syncthreads();

    // -------- proj: r0 = relu(a . W_in + b_in) . w~ -> rb0 ------------------
    if (act) {
        const float4* Wb4 = (const float4*)s_Wb;
        float zacc = 0.f;
#pragma unroll 4
        for (int jj = 0; jj < 128; jj++) {
            int j = (jj << 2) | sub;                 // 4-way split of j-range
            float4 wA = Wb4[2 * j];                  // w0..w3
            float4 wB = Wb4[2 * j + 1];              // w4, w5, b, pad
            float tv = wB.z + a0 * wA.x + a1 * wA.y + a2 * wA.z +
                       a3 * wA.w + a4 * wB.x + a5 * wB.y;
            zacc += fmaxf(tv, 0.f) * s_vt[j];
        }
        zacc += __shfl_xor(zacc, 1, 64);
        zacc += __shfl_xor(zacc, 2, 64);
        if (sub == 0) stAf(&rb0[node], zacc);
    }
    int gt = 1;
    group_bar(g_arrive, bx, NB_G, gt++);

    // -------- Horner: r_{l+1} = A r_l + gamma[l]; sc1 ping-pong (R4) --------
    for (int l = 0; l < DEPTH; l++) {
        if (act) {
            const float* rin = (l & 1) ? rb1 : rb0;
            float h0 = 0.f, h1 = 0.f, h2 = 0.f, h3 = 0.f;
            int pp = ns + sub;
            if (use_lds) {
                for (; pp + 12 < ne; pp += 16) {
                    h0 += ldAf(&rin[lds_e[pp - e_lo]]);
                    h1 += ldAf(&rin[lds_e[pp + 4 - e_lo]]);
                    h2 += ldAf(&rin[lds_e[pp + 8 - e_lo]]);
                    h3 += ldAf(&rin[lds_e[pp + 12 - e_lo]]);
                }
                for (; pp < ne; pp += 4) h0 += ldAf(&rin[lds_e[pp - e_lo]]);
            } else {
                for (; pp < ne; pp += 4) {
                    u64 ev = ld8(&esrc8[pp]);
                    while (!READY(ev)) { __builtin_amdgcn_s_sleep(1); ev = ld8(&esrc8[pp]); }
                    h0 += ldAf(&rin[(int)(unsigned)ev]);
                }
            }
            float hs = (h0 + h1) + (h2 + h3);
            hs += __shfl_xor(hs, 1, 64);
            hs += __shfl_xor(hs, 2, 64);
            if (sub == 0) {
                float res = hs + s_gam[l];
                if (l == DEPTH - 1) out[node] = res + b_out[0];
                else stAf(&((l & 1) ? rb0 : rb1)[node], res);
            }
        }
        if (l < DEPTH - 1) group_bar(g_arrive, bx, NB_G, gt++);
    }
}

// ---------------- launch ----------------

extern "C" void kernel_launch(void* const* d_in, const int* in_sizes, int n_in,
                              void* d_out, int out_size, void* d_ws, size_t ws_size,
                              hipStream_t stream) {
    const float* features = (const float*)d_in[0];  // [10000, 6]
    const float* W_in     = (const float*)d_in[1];  // [6, 512]
    const float* b_in     = (const float*)d_in[2];  // [512]
    const float* Ws       = (const float*)d_in[3];  // [10, 512, 512]
    const float* bs       = (const float*)d_in[4];  // [10, 512]
    const float* W_out    = (const float*)d_in[5];  // [512, 1]
    const float* b_out    = (const float*)d_in[6];  // [1]
    const int*   src      = (const int*)d_in[7];    // [160000]
    const int*   dst      = (const int*)d_in[8];    // [160000]
    float* out = (float*)d_out;                     // [10000]

    char* base = (char*)d_ws;
    // ---- zeroed region (flags/tags/deg/rb cleared every replay) ----
    int* g_arrive  = (int*)(base + 0);          // 40*128 -> 5120
    int* deg_done  = (int*)(base + 5120);       // 40*128 -> 10240
    int* scan_done = (int*)(base + 10240);      // 128   -> 10368
    u64* gamma8    = (u64*)(base + 10368);      // 128   -> 10496
    u64* vslab     = (u64*)(base + 10496);      // 11*512*8 = 45056 -> 55552
    int* deg       = (int*)(base + 55552);      // 40000 -> 95552 (pad 95616)
    u64* esrc8     = (u64*)(base + 95616);      // 1280000 -> 1375616
    float* rb0     = (float*)(base + 1375616);  // 40064 -> 1415680
    float* rb1     = (float*)(base + 1415680);  // 40064 -> 1455744
    const size_t MEMSET_END = 1455744;
    // ---- non-zeroed (fully overwritten before any read, each launch) ----
    int* row_ptr   = (int*)(base + 1455744);    // 40004 -> pad 1495808
    int* cursor    = (int*)(base + 1495808);    // 40000 -> 1535808

    // clear tags/flags/deg/rb each replay (captured in graph)
    hipMemsetAsync(base, 0, MEMSET_END, stream);

    gcn_mega<<<NB, BT, 0, stream>>>(features, W_in, b_in, Ws, bs, W_out, b_out,
                                    src, dst, out,
                                    g_arrive, deg_done, scan_done, gamma8,
                                    vslab, deg, esrc8, rb0, rb1,
                                    row_ptr, cursor);
}

// Round 9
// 205.110 us; speedup vs baseline: 1.0339x; 1.0044x over previous
//
#include <hip/hip_runtime.h>

// ============================================================================
// Algebraic collapse (layers 2..11 + head linear; A commutes with W):
//   out = A^10 x1 w~ + sum_l gamma_l A^(9-l) 1 + b_out
// Round-9: measured-best composition of proven-correct parts.
//   * graph front-end: R4's (fastest measured, absmax 0): 3 group barriers,
//     plain 4-byte sc1 esrc, block-0 scan. NO tagged esrc8 (R8 regression).
//   * chain: R8's (absmax 0): 33 x 1024 blocks, barrier-FREE tagged dataflow,
//     1 row/wave; ~1.5us/step vs ~4us/step barrier version (R4 critical path).
//   * rendezvous: graph blocks poll w~/gamma value-tags directly (R8-proven).
//   * proj + 10 Horner steps: R4/R8-identical sc1 ping-pong + group_bar.
// All cross-block mutable data via agent-scope relaxed atomics (sc1). No
// threadfence. No plain loads on shared mutable data (R6 lesson). No new
// barrier/geometry designs (R7 lesson).
// ============================================================================

#define N_NODES 10000
#define N_EDGES 160000
#define DEPTH   10

#define NB_G 40                  // graph blocks
#define NB_C 33                  // chain blocks (33*16 waves = 528 >= 513)
#define NB   (NB_G + NB_C)       // 73 blocks x 1024: all co-resident
#define BT   1024
#define NTHG (NB_G * BT)         // 40960 graph threads
#define NPB  250                 // nodes per graph block (40*250 = 10000)
#define ECAP 8192                // LDS edge-slice cap (expected ~4000)

typedef unsigned long long u64;

// ---- agent-scope (L3-coherent) accessors -----------------------------------
__device__ __forceinline__ int ldAi(const int* p) {
    return __hip_atomic_load(p, __ATOMIC_RELAXED, __HIP_MEMORY_SCOPE_AGENT);
}
__device__ __forceinline__ void stAi(int* p, int v) {
    __hip_atomic_store(p, v, __ATOMIC_RELAXED, __HIP_MEMORY_SCOPE_AGENT);
}
__device__ __forceinline__ float ldAf(const float* p) {
    return __hip_atomic_load(p, __ATOMIC_RELAXED, __HIP_MEMORY_SCOPE_AGENT);
}
__device__ __forceinline__ void stAf(float* p, float v) {
    __hip_atomic_store(p, v, __ATOMIC_RELAXED, __HIP_MEMORY_SCOPE_AGENT);
}
__device__ __forceinline__ u64 ld8(const u64* p) {
    return __hip_atomic_load(p, __ATOMIC_RELAXED, __HIP_MEMORY_SCOPE_AGENT);
}
__device__ __forceinline__ void st8(u64* p, u64 v) {
    __hip_atomic_store(p, v, __ATOMIC_RELAXED, __HIP_MEMORY_SCOPE_AGENT);
}
__device__ __forceinline__ u64 packf(float f) {
    union { float f; unsigned u; } c; c.f = f;
    return (1ull << 32) | (u64)c.u;
}
__device__ __forceinline__ float unpackf(u64 v) {
    union { unsigned u; float f; } c; c.u = (unsigned)v;
    return c.f;
}
#define READY(v) ((unsigned)((v) >> 32) != 0u)

__device__ __forceinline__ float pollf(const u64* p) {
    u64 v = ld8(p);
    while (!READY(v)) { __builtin_amdgcn_s_sleep(1); v = ld8(p); }
    return unpackf(v);
}

// ---- R4-proven group barrier: stride-32 flags, one poll thread per flag ----
__device__ __forceinline__ void group_bar(int* flags, int gi, int n, int target) {
    const int tx = threadIdx.x;
    asm volatile("s_waitcnt vmcnt(0)" ::: "memory");  // this wave's sc1 at L3
    __syncthreads();                                  // all waves drained
    if (tx == 0) stAi(&flags[gi * 32], target);
    if (tx < n && tx != gi) {
        while (ldAi(&flags[tx * 32]) < target) __builtin_amdgcn_s_sleep(1);
    }
    __syncthreads();
}

extern "C" __global__ void __launch_bounds__(BT, 1) gcn_mega(
    const float* __restrict__ features, const float* __restrict__ W_in,
    const float* __restrict__ b_in, const float* __restrict__ Ws,
    const float* __restrict__ bs, const float* __restrict__ W_out,
    const float* __restrict__ b_out, const int* __restrict__ src,
    const int* __restrict__ dst, float* __restrict__ out,
    int* g_arrive, u64* gamma8, u64* vslab, int* deg, int* esrc,
    float* rb0, float* rb1, int* row_ptr, int* cursor)
{
    __shared__ int   lds_e[ECAP];     // 32 KB  edge slice (src ids)
    __shared__ float s_Wb[4096];      // 16 KB  [512][8]: {W_in col (6), b, pad}
    __shared__ float s_vt[512];       //  2 KB  vtilde
    __shared__ float s_gam[16];
    __shared__ int   s_info[2];
    __shared__ int   s_wsum[16];

    const int tx = threadIdx.x;
    const int bx = blockIdx.x;

    // ======================= CHAIN GROUP (blocks >= NB_G) ===================
    // R8-proven tagged dataflow, no barriers. Wave cw owns row cw (512=gamma).
    if (bx >= NB_G) {
        const int gi   = bx - NB_G;
        const int cw   = gi * 16 + (tx >> 6);         // 0..527
        const int lane = tx & 63;
        if (cw > 512) return;
        for (int s = 0; s < DEPTH; s++) {
            const int l = 9 - s;
            const float* rowp = (cw < 512)
                ? (Ws + (size_t)l * (512 * 512) + (size_t)cw * 512)
                : (bs + (size_t)l * 512);
            float wrow[8];
#pragma unroll
            for (int c = 0; c < 8; c++) wrow[c] = rowp[lane + 64 * c];
            float vin[8];
            if (s == 0) {
#pragma unroll
                for (int c = 0; c < 8; c++) vin[c] = W_out[lane + 64 * c];
            } else {
                const u64* vb = vslab + (size_t)s * 512;
                u64 raw[8];
#pragma unroll
                for (int c = 0; c < 8; c++) raw[c] = ld8(vb + lane + 64 * c);
                for (;;) {
                    bool ok = true;
#pragma unroll
                    for (int c = 0; c < 8; c++)
                        if (!READY(raw[c])) { ok = false; raw[c] = ld8(vb + lane + 64 * c); }
                    if (ok) break;
                    __builtin_amdgcn_s_sleep(1);
                }
#pragma unroll
                for (int c = 0; c < 8; c++) vin[c] = unpackf(raw[c]);
            }
            float acc = 0.f;
#pragma unroll
            for (int c = 0; c < 8; c++) acc += wrow[c] * vin[c];
#pragma unroll
            for (int off = 32; off; off >>= 1) acc += __shfl_xor(acc, off, 64);
            if (lane == 0) {
                if (cw < 512) st8(vslab + (size_t)(s + 1) * 512 + cw, packf(acc));
                else          st8(gamma8 + l, packf(acc));
            }
        }
        return;   // w~ tags in vslab[10] ARE the rendezvous
    }

    // ======================= GRAPH GROUP (blocks < NB_G) ====================
    const int gi = bx;
    int gt = 1;

    // -------- P0: degree count + per-block W_in pack ------------------------
    {
        const int t0 = bx * BT + tx;
        for (int e = t0; e < N_EDGES; e += NTHG) atomicAdd(&deg[dst[e]], 1);
    }
    for (int idx = tx; idx < 4096; idx += BT) {
        int j = idx >> 3, k = idx & 7;
        float v = 0.f;
        if (k < 6) v = W_in[k * 512 + j];          // read-only cached loads
        else if (k == 6) v = b_in[j];
        s_Wb[idx] = v;
    }
    group_bar(g_arrive, gi, NB_G, gt++);

    // -------- P1: prefix scan (graph block 0, shuffle-based) ----------------
    if (bx == 0) {
        const int lane = tx & 63, wid = tx >> 6;    // 16 waves
        const bool sact = tx < 1000;                // 1000 x 10 = 10000
        int lv[10];
        int ssum = 0;
        if (sact) {
#pragma unroll
            for (int i = 0; i < 10; i++) { lv[i] = ldAi(&deg[tx * 10 + i]); ssum += lv[i]; }
        }
        int v = ssum;                               // wave inclusive scan
#pragma unroll
        for (int off = 1; off < 64; off <<= 1) {
            int u = __shfl_up(v, off, 64);
            if (lane >= off) v += u;
        }
        if (lane == 63) s_wsum[wid] = v;
        __syncthreads();
        if (wid == 0) {                             // scan the 16 wave totals
            int w = (lane < 16) ? s_wsum[lane] : 0;
#pragma unroll
            for (int off = 1; off < 16; off <<= 1) {
                int u = __shfl_up(w, off, 64);
                if (lane >= off) w += u;
            }
            if (lane < 16) s_wsum[lane] = w;
        }
        __syncthreads();
        if (sact) {
            int run = (wid ? s_wsum[wid - 1] : 0) + (v - ssum);  // exclusive
#pragma unroll
            for (int i = 0; i < 10; i++) {
                stAi(&row_ptr[tx * 10 + i], run);
                stAi(&cursor[tx * 10 + i], run);
                run += lv[i];
            }
            if (tx == 999) stAi(&row_ptr[N_NODES], run);
        }
    }
    group_bar(g_arrive, gi, NB_G, gt++);

    // -------- P2: CSR fill (plain 4-byte sc1 entries; R4-proven) ------------
    {
        const int t0 = bx * BT + tx;
        for (int e = t0; e < N_EDGES; e += NTHG) {
            int d = dst[e];
            int sv = src[e];
            int pos = atomicAdd(&cursor[d], 1);
            stAi(&esrc[pos], sv);
        }
    }
    group_bar(g_arrive, gi, NB_G, gt++);

    // -------- P3: stage edge slice -> LDS; aggregate features ---------------
    if (tx == 0) {
        s_info[0] = ldAi(&row_ptr[bx * NPB]);
        s_info[1] = ldAi(&row_ptr[bx * NPB + NPB]);
    }
    __syncthreads();
    const int e_lo = s_info[0];
    const int slen = s_info[1] - e_lo;
    const bool use_lds = (slen <= ECAP);
    if (use_lds) {
        for (int i = tx; i < slen; i += BT) lds_e[i] = ldAi(&esrc[e_lo + i]);
    }
    __syncthreads();

    const int node = bx * NPB + (tx >> 2);          // 4 threads/node
    const int sub  = tx & 3;
    const bool act = tx < 4 * NPB;                  // 1000 active threads
    int ns = 0, ne = 0;
    float a0 = 0.f, a1 = 0.f, a2 = 0.f, a3 = 0.f, a4 = 0.f, a5 = 0.f;
    if (act) {
        ns = ldAi(&row_ptr[node]);
        ne = ldAi(&row_ptr[node + 1]);
        for (int pp = ns + sub; pp < ne; pp += 4) {
            int j;
            if (use_lds) j = lds_e[pp - e_lo];
            else         j = ldAi(&esrc[pp]);
            const float2* f = (const float2*)(features + (size_t)j * 6);
            float2 f0 = f[0], f1 = f[1], f2 = f[2];
            a0 += f0.x; a1 += f0.y; a2 += f1.x;
            a3 += f1.y; a4 += f2.x; a5 += f2.y;
        }
        a0 += __shfl_xor(a0, 1, 64); a0 += __shfl_xor(a0, 2, 64);
        a1 += __shfl_xor(a1, 1, 64); a1 += __shfl_xor(a1, 2, 64);
        a2 += __shfl_xor(a2, 1, 64); a2 += __shfl_xor(a2, 2, 64);
        a3 += __shfl_xor(a3, 1, 64); a3 += __shfl_xor(a3, 2, 64);
        a4 += __shfl_xor(a4, 1, 64); a4 += __shfl_xor(a4, 2, 64);
        a5 += __shfl_xor(a5, 1, 64); a5 += __shfl_xor(a5, 2, 64);
    }

    // -------- rendezvous: poll w~/gamma value-tags (R8-proven) --------------
    if (tx < 512) s_vt[tx] = pollf(vslab + 10 * 512 + tx);
    else if (tx < 512 + DEPTH) s_gam[tx - 512] = pollf(gamma8 + (tx - 512));
    __syncthreads();

    // -------- proj: r0 = relu(a . W_in + b_in) . w~ -> rb0 ------------------
    if (act) {
        const float4* Wb4 = (const float4*)s_Wb;
        float zacc = 0.f;
#pragma unroll 4
        for (int jj = 0; jj < 128; jj++) {
            int j = (jj << 2) | sub;                // 4-way split of j-range
            float4 wA = Wb4[2 * j];                 // w0..w3
            float4 wB = Wb4[2 * j + 1];             // w4, w5, b, pad
            float tv = wB.z + a0 * wA.x + a1 * wA.y + a2 * wA.z +
                       a3 * wA.w + a4 * wB.x + a5 * wB.y;
            zacc += fmaxf(tv, 0.f) * s_vt[j];
        }
        zacc += __shfl_xor(zacc, 1, 64);
        zacc += __shfl_xor(zacc, 2, 64);
        if (sub == 0) stAf(&rb0[node], zacc);
    }
    group_bar(g_arrive, gi, NB_G, gt++);

    // -------- Horner: r_{l+1} = A r_l + gamma[l]; sc1 ping-pong (proven) ----
    for (int l = 0; l < DEPTH; l++) {
        if (act) {
            const float* rin = (l & 1) ? rb1 : rb0;
            float h0 = 0.f, h1 = 0.f, h2 = 0.f, h3 = 0.f;
            int pp = ns + sub;
            if (use_lds) {
                for (; pp + 12 < ne; pp += 16) {
                    h0 += ldAf(&rin[lds_e[pp - e_lo]]);
                    h1 += ldAf(&rin[lds_e[pp + 4 - e_lo]]);
                    h2 += ldAf(&rin[lds_e[pp + 8 - e_lo]]);
                    h3 += ldAf(&rin[lds_e[pp + 12 - e_lo]]);
                }
                for (; pp < ne; pp += 4) h0 += ldAf(&rin[lds_e[pp - e_lo]]);
            } else {
                for (; pp < ne; pp += 4) h0 += ldAf(&rin[ldAi(&esrc[pp])]);
            }
            float hs = (h0 + h1) + (h2 + h3);
            hs += __shfl_xor(hs, 1, 64);
            hs += __shfl_xor(hs, 2, 64);
            if (sub == 0) {
                float res = hs + s_gam[l];
                if (l == DEPTH - 1) out[node] = res + b_out[0];
                else stAf(&((l & 1) ? rb0 : rb1)[node], res);
            }
        }
        if (l < DEPTH - 1) group_bar(g_arrive, gi, NB_G, gt++);
    }
}

// ---------------- launch ----------------

extern "C" void kernel_launch(void* const* d_in, const int* in_sizes, int n_in,
                              void* d_out, int out_size, void* d_ws, size_t ws_size,
                              hipStream_t stream) {
    const float* features = (const float*)d_in[0];  // [10000, 6]
    const float* W_in     = (const float*)d_in[1];  // [6, 512]
    const float* b_in     = (const float*)d_in[2];  // [512]
    const float* Ws       = (const float*)d_in[3];  // [10, 512, 512]
    const float* bs       = (const float*)d_in[4];  // [10, 512]
    const float* W_out    = (const float*)d_in[5];  // [512, 1]
    const float* b_out    = (const float*)d_in[6];  // [1]
    const int*   src      = (const int*)d_in[7];    // [160000]
    const int*   dst      = (const int*)d_in[8];    // [160000]
    float* out = (float*)d_out;                     // [10000]

    char* base = (char*)d_ws;
    // ---- zeroed region (flags/tags/deg/rb cleared every replay) ----
    int*   g_arrive = (int*)(base + 0);         // 40*128 -> 5120
    u64*   gamma8   = (u64*)(base + 5120);      // 128    -> 5248
    u64*   vslab    = (u64*)(base + 5248);      // 11*512*8 = 45056 -> 50304
    int*   deg      = (int*)(base + 50304);     // 40000  -> 90304 (pad 90368)
    float* rb0      = (float*)(base + 90368);   // 40064  -> 130432
    float* rb1      = (float*)(base + 130432);  // 40064  -> 170496
    const size_t MEMSET_END = 170496;
    // ---- non-zeroed (fully overwritten before any read, each launch) ----
    int* esrc       = (int*)(base + 170496);    // 640000 -> 810496
    int* row_ptr    = (int*)(base + 810496);    // 40004  -> 850500 (pad 850560)
    int* cursor     = (int*)(base + 850560);    // 40000  -> 890560

    // clear flags/tags/deg/rb each replay (captured in graph)
    hipMemsetAsync(base, 0, MEMSET_END, stream);

    gcn_mega<<<NB, BT, 0, stream>>>(features, W_in, b_in, Ws, bs, W_out, b_out,
                                    src, dst, out,
                                    g_arrive, gamma8, vslab, deg, esrc,
                                    rb0, rb1, row_ptr, cursor);
}

// Round 10
// 201.787 us; speedup vs baseline: 1.0509x; 1.0165x over previous
//
#include <hip/hip_runtime.h>

// ============================================================================
// Algebraic collapse (layers 2..11 + head linear; A commutes with W):
//   out = A^10 x1 w~ + sum_l gamma_l A^(9-l) 1 + b_out
// Round-10: R4 structure (fastest correct: 112us kernel) with a FAST CHAIN.
//   * chain: 5 blocks, 8 rows/wave (64 working waves + 1 gamma wave),
//     software-pipelined weight prefetch (next step's rows loaded into VGPRs
//     BEFORE the barrier -> HBM latency hides under barrier RTT), 5-block
//     group_bar per step, rdv one-shot flags at end (R4-proven pattern).
//   * graph group: R4/R9 front-end verbatim (3 barriers, plain 4B sc1 esrc),
//     rendezvous = poll 5 rdv flags then plain ldA vtilde/gamma (R4-proven;
//     NO tag-polling by 21K threads -- that was R8/R9's +23us regression).
//   * proj + 10 Horner steps: R4/R9-identical sc1 ping-pong + group_bar.
// All cross-block mutable data via agent-scope relaxed atomics (sc1).
// ============================================================================

#define N_NODES 10000
#define N_EDGES 160000
#define DEPTH   10

#define NB_G 40                  // graph blocks
#define NB_C 5                   // chain blocks (80 waves; 64 rows + 1 gamma)
#define NB   (NB_G + NB_C)       // 45 blocks x 1024: all co-resident
#define BT   1024
#define NTHG (NB_G * BT)         // 40960 graph threads
#define NPB  250                 // nodes per graph block (40*250 = 10000)
#define ECAP 8192                // LDS edge-slice cap (expected ~4000)

typedef unsigned long long u64;

// ---- agent-scope (L3-coherent) accessors -----------------------------------
__device__ __forceinline__ int ldAi(const int* p) {
    return __hip_atomic_load(p, __ATOMIC_RELAXED, __HIP_MEMORY_SCOPE_AGENT);
}
__device__ __forceinline__ void stAi(int* p, int v) {
    __hip_atomic_store(p, v, __ATOMIC_RELAXED, __HIP_MEMORY_SCOPE_AGENT);
}
__device__ __forceinline__ float ldAf(const float* p) {
    return __hip_atomic_load(p, __ATOMIC_RELAXED, __HIP_MEMORY_SCOPE_AGENT);
}
__device__ __forceinline__ void stAf(float* p, float v) {
    __hip_atomic_store(p, v, __ATOMIC_RELAXED, __HIP_MEMORY_SCOPE_AGENT);
}
__device__ __forceinline__ u64 ld8(const u64* p) {
    return __hip_atomic_load(p, __ATOMIC_RELAXED, __HIP_MEMORY_SCOPE_AGENT);
}

// ---- R4-proven group barrier: stride-32 flags, one poll thread per flag ----
__device__ __forceinline__ void group_bar(int* flags, int gi, int n, int target) {
    const int tx = threadIdx.x;
    asm volatile("s_waitcnt vmcnt(0)" ::: "memory");  // this wave's sc1 at L3
    __syncthreads();                                  // all waves drained
    if (tx == 0) stAi(&flags[gi * 32], target);
    if (tx < n && tx != gi) {
        while (ldAi(&flags[tx * 32]) < target) __builtin_amdgcn_s_sleep(1);
    }
    __syncthreads();
}

extern "C" __global__ void __launch_bounds__(BT, 1) gcn_mega(
    const float* __restrict__ features, const float* __restrict__ W_in,
    const float* __restrict__ b_in, const float* __restrict__ Ws,
    const float* __restrict__ bs, const float* __restrict__ W_out,
    const float* __restrict__ b_out, const int* __restrict__ src,
    const int* __restrict__ dst, float* __restrict__ out,
    int* g_arrive, int* c_arrive, int* rdv, float* gamma_f, float* vbufs,
    int* deg, int* esrc, float* rb0, float* rb1, int* row_ptr, int* cursor)
{
    __shared__ int   lds_e[ECAP];     // 32 KB  edge slice (src ids)
    __shared__ float s_Wb[4096];      // 16 KB  [512][8]: {W_in col (6), b, pad}
    __shared__ float s_vt[512];       //  2 KB  vtilde
    __shared__ float s_gam[16];
    __shared__ int   s_info[2];
    __shared__ int   s_wsum[16];

    const int tx = threadIdx.x;
    const int bx = blockIdx.x;

    // ======================= CHAIN GROUP (blocks >= NB_G) ===================
    // 8 rows/wave, pipelined weight prefetch, 5-block barrier per step.
    if (bx >= NB_G) {
        const int ci   = bx - NB_G;                // 0..4
        const int gw   = ci * 16 + (tx >> 6);      // 0..79
        const int lane = tx & 63;
        const bool rows_job  = (gw < 64);          // rows 8gw .. 8gw+7
        const bool gamma_job = (gw == 64);
        const int  R0 = gw * 8;

        float w[8][8];                             // 64 VGPRs: this step's rows
        // prefetch step-0 weights (l = 9)
        if (rows_job) {
            const float* Wl = Ws + (size_t)9 * 512 * 512;
#pragma unroll
            for (int r = 0; r < 8; r++) {
                const float4* p = (const float4*)(Wl + (size_t)(R0 + r) * 512 + lane * 8);
                float4 x = p[0], y = p[1];
                w[r][0] = x.x; w[r][1] = x.y; w[r][2] = x.z; w[r][3] = x.w;
                w[r][4] = y.x; w[r][5] = y.y; w[r][6] = y.z; w[r][7] = y.w;
            }
        } else if (gamma_job) {
            const float4* p = (const float4*)(bs + (size_t)9 * 512 + lane * 8);
            float4 x = p[0], y = p[1];
            w[0][0] = x.x; w[0][1] = x.y; w[0][2] = x.z; w[0][3] = x.w;
            w[0][4] = y.x; w[0][5] = y.y; w[0][6] = y.z; w[0][7] = y.w;
        }

        for (int s = 0; s < DEPTH; s++) {
            if (s > 0) group_bar(c_arrive, ci, NB_C, s);
            // ---- read vin (elements lane*8 .. lane*8+7) ----
            float vin[8];
            if (s == 0) {
                const float4* p = (const float4*)(W_out + lane * 8);
                float4 x = p[0], y = p[1];
                vin[0] = x.x; vin[1] = x.y; vin[2] = x.z; vin[3] = x.w;
                vin[4] = y.x; vin[5] = y.y; vin[6] = y.z; vin[7] = y.w;
            } else {
                const u64* vb = (const u64*)(vbufs + (s & 1) * 512);
#pragma unroll
                for (int k = 0; k < 4; k++) {
                    union { u64 u; float f[2]; } c;
                    c.u = ld8(vb + lane * 4 + k);
                    vin[2 * k]     = c.f[0];
                    vin[2 * k + 1] = c.f[1];
                }
            }
            // ---- compute + store ----
            if (rows_job) {
                float* vout = vbufs + ((s + 1) & 1) * 512;
#pragma unroll
                for (int r = 0; r < 8; r++) {
                    float acc = 0.f;
#pragma unroll
                    for (int k = 0; k < 8; k++) acc += w[r][k] * vin[k];
#pragma unroll
                    for (int off = 32; off; off >>= 1) acc += __shfl_xor(acc, off, 64);
                    if (lane == r) stAf(&vout[R0 + r], acc);   // 8 lanes store in parallel
                }
            } else if (gamma_job) {
                float acc = 0.f;
#pragma unroll
                for (int k = 0; k < 8; k++) acc += w[0][k] * vin[k];
#pragma unroll
                for (int off = 32; off; off >>= 1) acc += __shfl_xor(acc, off, 64);
                if (lane == 0) stAf(&gamma_f[9 - s], acc);
            }
            // ---- prefetch next step's weights (hides under the barrier) ----
            if (s < DEPTH - 1) {
                const int ln = 8 - s;                         // l for step s+1
                if (rows_job) {
                    const float* Wl = Ws + (size_t)ln * 512 * 512;
#pragma unroll
                    for (int r = 0; r < 8; r++) {
                        const float4* p = (const float4*)(Wl + (size_t)(R0 + r) * 512 + lane * 8);
                        float4 x = p[0], y = p[1];
                        w[r][0] = x.x; w[r][1] = x.y; w[r][2] = x.z; w[r][3] = x.w;
                        w[r][4] = y.x; w[r][5] = y.y; w[r][6] = y.z; w[r][7] = y.w;
                    }
                } else if (gamma_job) {
                    const float4* p = (const float4*)(bs + (size_t)ln * 512 + lane * 8);
                    float4 x = p[0], y = p[1];
                    w[0][0] = x.x; w[0][1] = x.y; w[0][2] = x.z; w[0][3] = x.w;
                    w[0][4] = y.x; w[0][5] = y.y; w[0][6] = y.z; w[0][7] = y.w;
                }
            }
        }
        // publish: one-shot rdv flags (R4-proven), then exit
        asm volatile("s_waitcnt vmcnt(0)" ::: "memory");
        __syncthreads();
        if (tx == 0) stAi(&rdv[ci * 32], 1);
        return;
    }

    // ======================= GRAPH GROUP (blocks < NB_G) ====================
    const int gi = bx;
    int gt = 1;

    // -------- P0: degree count + per-block W_in pack ------------------------
    {
        const int t0 = bx * BT + tx;
        for (int e = t0; e < N_EDGES; e += NTHG) atomicAdd(&deg[dst[e]], 1);
    }
    for (int idx = tx; idx < 4096; idx += BT) {
        int j = idx >> 3, k = idx & 7;
        float v = 0.f;
        if (k < 6) v = W_in[k * 512 + j];          // read-only cached loads
        else if (k == 6) v = b_in[j];
        s_Wb[idx] = v;
    }
    group_bar(g_arrive, gi, NB_G, gt++);

    // -------- P1: prefix scan (graph block 0, shuffle-based) ----------------
    if (bx == 0) {
        const int lane = tx & 63, wid = tx >> 6;    // 16 waves
        const bool sact = tx < 1000;                // 1000 x 10 = 10000
        int lv[10];
        int ssum = 0;
        if (sact) {
#pragma unroll
            for (int i = 0; i < 10; i++) { lv[i] = ldAi(&deg[tx * 10 + i]); ssum += lv[i]; }
        }
        int v = ssum;                               // wave inclusive scan
#pragma unroll
        for (int off = 1; off < 64; off <<= 1) {
            int u = __shfl_up(v, off, 64);
            if (lane >= off) v += u;
        }
        if (lane == 63) s_wsum[wid] = v;
        __syncthreads();
        if (wid == 0) {                             // scan the 16 wave totals
            int w = (lane < 16) ? s_wsum[lane] : 0;
#pragma unroll
            for (int off = 1; off < 16; off <<= 1) {
                int u = __shfl_up(w, off, 64);
                if (lane >= off) w += u;
            }
            if (lane < 16) s_wsum[lane] = w;
        }
        __syncthreads();
        if (sact) {
            int run = (wid ? s_wsum[wid - 1] : 0) + (v - ssum);  // exclusive
#pragma unroll
            for (int i = 0; i < 10; i++) {
                stAi(&row_ptr[tx * 10 + i], run);
                stAi(&cursor[tx * 10 + i], run);
                run += lv[i];
            }
            if (tx == 999) stAi(&row_ptr[N_NODES], run);
        }
    }
    group_bar(g_arrive, gi, NB_G, gt++);

    // -------- P2: CSR fill (plain 4-byte sc1 entries; R4-proven) ------------
    {
        const int t0 = bx * BT + tx;
        for (int e = t0; e < N_EDGES; e += NTHG) {
            int d = dst[e];
            int sv = src[e];
            int pos = atomicAdd(&cursor[d], 1);
            stAi(&esrc[pos], sv);
        }
    }
    group_bar(g_arrive, gi, NB_G, gt++);

    // -------- P3: stage edge slice -> LDS; aggregate features ---------------
    if (tx == 0) {
        s_info[0] = ldAi(&row_ptr[bx * NPB]);
        s_info[1] = ldAi(&row_ptr[bx * NPB + NPB]);
    }
    __syncthreads();
    const int e_lo = s_info[0];
    const int slen = s_info[1] - e_lo;
    const bool use_lds = (slen <= ECAP);
    if (use_lds) {
        for (int i = tx; i < slen; i += BT) lds_e[i] = ldAi(&esrc[e_lo + i]);
    }
    __syncthreads();

    const int node = bx * NPB + (tx >> 2);          // 4 threads/node
    const int sub  = tx & 3;
    const bool act = tx < 4 * NPB;                  // 1000 active threads
    int ns = 0, ne = 0;
    float a0 = 0.f, a1 = 0.f, a2 = 0.f, a3 = 0.f, a4 = 0.f, a5 = 0.f;
    if (act) {
        ns = ldAi(&row_ptr[node]);
        ne = ldAi(&row_ptr[node + 1]);
        for (int pp = ns + sub; pp < ne; pp += 4) {
            int j;
            if (use_lds) j = lds_e[pp - e_lo];
            else         j = ldAi(&esrc[pp]);
            const float2* f = (const float2*)(features + (size_t)j * 6);
            float2 f0 = f[0], f1 = f[1], f2 = f[2];
            a0 += f0.x; a1 += f0.y; a2 += f1.x;
            a3 += f1.y; a4 += f2.x; a5 += f2.y;
        }
        a0 += __shfl_xor(a0, 1, 64); a0 += __shfl_xor(a0, 2, 64);
        a1 += __shfl_xor(a1, 1, 64); a1 += __shfl_xor(a1, 2, 64);
        a2 += __shfl_xor(a2, 1, 64); a2 += __shfl_xor(a2, 2, 64);
        a3 += __shfl_xor(a3, 1, 64); a3 += __shfl_xor(a3, 2, 64);
        a4 += __shfl_xor(a4, 1, 64); a4 += __shfl_xor(a4, 2, 64);
        a5 += __shfl_xor(a5, 1, 64); a5 += __shfl_xor(a5, 2, 64);
    }

    // -------- rendezvous: poll 5 one-shot rdv flags, then plain sc1 reads ---
    if (tx < NB_C) {
        while (ldAi(&rdv[tx * 32]) < 1) __builtin_amdgcn_s_sleep(1);
    }
    __syncthreads();
    if (tx < 512) s_vt[tx] = ldAf(&vbufs[tx]);      // final w~ in buffer 0
    else if (tx < 512 + DEPTH) s_gam[tx - 512] = ldAf(&gamma_f[tx - 512]);
    __syncthreads();

    // -------- proj: r0 = relu(a . W_in + b_in) . w~ -> rb0 ------------------
    if (act) {
        const float4* Wb4 = (const float4*)s_Wb;
        float zacc = 0.f;
#pragma unroll 4
        for (int jj = 0; jj < 128; jj++) {
            int j = (jj << 2) | sub;                // 4-way split of j-range
            float4 wA = Wb4[2 * j];                 // w0..w3
            float4 wB = Wb4[2 * j + 1];             // w4, w5, b, pad
            float tv = wB.z + a0 * wA.x + a1 * wA.y + a2 * wA.z +
                       a3 * wA.w + a4 * wB.x + a5 * wB.y;
            zacc += fmaxf(tv, 0.f) * s_vt[j];
        }
        zacc += __shfl_xor(zacc, 1, 64);
        zacc += __shfl_xor(zacc, 2, 64);
        if (sub == 0) stAf(&rb0[node], zacc);
    }
    group_bar(g_arrive, gi, NB_G, gt++);

    // -------- Horner: r_{l+1} = A r_l + gamma[l]; sc1 ping-pong (proven) ----
    for (int l = 0; l < DEPTH; l++) {
        if (act) {
            const float* rin = (l & 1) ? rb1 : rb0;
            float h0 = 0.f, h1 = 0.f, h2 = 0.f, h3 = 0.f;
            int pp = ns + sub;
            if (use_lds) {
                for (; pp + 12 < ne; pp += 16) {
                    h0 += ldAf(&rin[lds_e[pp - e_lo]]);
                    h1 += ldAf(&rin[lds_e[pp + 4 - e_lo]]);
                    h2 += ldAf(&rin[lds_e[pp + 8 - e_lo]]);
                    h3 += ldAf(&rin[lds_e[pp + 12 - e_lo]]);
                }
                for (; pp < ne; pp += 4) h0 += ldAf(&rin[lds_e[pp - e_lo]]);
            } else {
                for (; pp < ne; pp += 4) h0 += ldAf(&rin[ldAi(&esrc[pp])]);
            }
            float hs = (h0 + h1) + (h2 + h3);
            hs += __shfl_xor(hs, 1, 64);
            hs += __shfl_xor(hs, 2, 64);
            if (sub == 0) {
                float res = hs + s_gam[l];
                if (l == DEPTH - 1) out[node] = res + b_out[0];
                else stAf(&((l & 1) ? rb0 : rb1)[node], res);
            }
        }
        if (l < DEPTH - 1) group_bar(g_arrive, gi, NB_G, gt++);
    }
}

// ---------------- launch ----------------

extern "C" void kernel_launch(void* const* d_in, const int* in_sizes, int n_in,
                              void* d_out, int out_size, void* d_ws, size_t ws_size,
                              hipStream_t stream) {
    const float* features = (const float*)d_in[0];  // [10000, 6]
    const float* W_in     = (const float*)d_in[1];  // [6, 512]
    const float* b_in     = (const float*)d_in[2];  // [512]
    const float* Ws       = (const float*)d_in[3];  // [10, 512, 512]
    const float* bs       = (const float*)d_in[4];  // [10, 512]
    const float* W_out    = (const float*)d_in[5];  // [512, 1]
    const float* b_out    = (const float*)d_in[6];  // [1]
    const int*   src      = (const int*)d_in[7];    // [160000]
    const int*   dst      = (const int*)d_in[8];    // [160000]
    float* out = (float*)d_out;                     // [10000]

    char* base = (char*)d_ws;
    // ---- zeroed region (flags/deg/rb cleared every replay) ----
    int*   g_arrive = (int*)(base + 0);         // 40*128 -> 5120
    int*   c_arrive = (int*)(base + 5120);      // 5*128  -> 5760
    int*   rdv      = (int*)(base + 5760);      // 5*128  -> 6400
    float* gamma_f  = (float*)(base + 6400);    // 64     -> 6464 (pad 6528)
    int*   deg      = (int*)(base + 6528);      // 40000  -> 46528 (pad 46592)
    float* rb0      = (float*)(base + 46592);   // 40064  -> 86656
    float* rb1      = (float*)(base + 86656);   // 40064  -> 126720
    const size_t MEMSET_END = 126720;
    // ---- non-zeroed (fully overwritten before any read, each launch) ----
    float* vbufs    = (float*)(base + 126720);  // 2*512*4 = 4096 -> 130816
    int*   esrc     = (int*)(base + 130816);    // 640000 -> 770816
    int*   row_ptr  = (int*)(base + 770816);    // 40004  -> 810820 (pad 810880)
    int*   cursor   = (int*)(base + 810880);    // 40000  -> 850880

    // clear flags/deg/rb each replay (captured in graph)
    hipMemsetAsync(base, 0, MEMSET_END, stream);

    gcn_mega<<<NB, BT, 0, stream>>>(features, W_in, b_in, Ws, bs, W_out, b_out,
                                    src, dst, out,
                                    g_arrive, c_arrive, rdv, gamma_f, vbufs,
                                    deg, esrc, rb0, rb1, row_ptr, cursor);
}